// Round 19
// baseline (604.829 us; speedup 1.0000x reference)
//
#include <hip/hip_runtime.h>
#include <hip/hip_bf16.h>

#define T_SEQ 2048
#define CDIM 512
#define HDIM 8
#define DHEAD 64
#define BT 4096   // B*T

// f32 -> bf16 (round-to-nearest-even)
__device__ __forceinline__ unsigned short f2b(float x) {
    unsigned u = __float_as_uint(x);
    u += 0x7fff + ((u >> 16) & 1);
    return (unsigned short)(u >> 16);
}
// bf16 -> f32 (exact)
__device__ __forceinline__ float b2f(unsigned short v) {
    return __uint_as_float((unsigned)v << 16);
}

// ---------------------------------------------------------------------------
// Kernel 0: tanh of the three weight matrices (once; 3*512*512 values).
// ---------------------------------------------------------------------------
__global__ __launch_bounds__(256) void wprep(
    const float* __restrict__ wq, const float* __restrict__ wk, const float* __restrict__ wv,
    float* __restrict__ wqa, float* __restrict__ wka, float* __restrict__ wva)
{
    const int NW = CDIM * CDIM / 4;   // 65536 float4 per matrix
    int idx = blockIdx.x * 256 + threadIdx.x;
    const float4* src; float4* dst; int off;
    if (idx < NW)            { src = (const float4*)wq; dst = (float4*)wqa; off = idx; }
    else if (idx < 2 * NW)   { src = (const float4*)wk; dst = (float4*)wka; off = idx - NW; }
    else                     { src = (const float4*)wv; dst = (float4*)wva; off = idx - 2 * NW; }
    float4 t = src[off];
    t.x = tanhf(t.x); t.y = tanhf(t.y); t.z = tanhf(t.z); t.w = tanhf(t.w);
    dst[off] = t;
}

// ---------------------------------------------------------------------------
// Kernel 1: L1-cdist projection. x-tanh fused into A-staging; weights
// pre-tanh'd by wprep. 64x128 tile, 256 threads, 4x8 micro-tile. (256,1).
// ---------------------------------------------------------------------------
#define PSTR 36
__global__ __launch_bounds__(256, 1) void proj_l1(
    const float* __restrict__ x,
    const float* __restrict__ wqa, const float* __restrict__ wka, const float* __restrict__ wva,
    const float* __restrict__ gq,  const float* __restrict__ gk,  const float* __restrict__ gv,
    float* __restrict__ oq, float* __restrict__ okk, float* __restrict__ ov)
{
    __shared__ float As[64][PSTR];
    __shared__ float Bs[128][PSTR];

    const int z = blockIdx.z;
    const float* w    = (z == 0) ? wqa : (z == 1) ? wka : wva;
    const float* gain = (z == 0) ? gq  : (z == 1) ? gk  : gv;
    float* outp       = (z == 0) ? oq  : (z == 1) ? okk : ov;

    const int row0 = blockIdx.y * 64;
    const int col0 = blockIdx.x * 128;
    const int tid = threadIdx.x;
    const int tx = tid & 15, ty = tid >> 4;

    float acc[4][8];
    #pragma unroll
    for (int i = 0; i < 4; ++i)
        #pragma unroll
        for (int j = 0; j < 8; ++j) acc[i][j] = 0.f;

    for (int k0 = 0; k0 < CDIM; k0 += 32) {
        __syncthreads();
        #pragma unroll
        for (int q = 0; q < 2; ++q) {
            const int fi = tid + 256 * q;
            const int r = fi >> 3, c4 = 4 * (fi & 7);
            float4 t = *(const float4*)&x[(size_t)(row0 + r) * CDIM + k0 + c4];
            t.x = tanhf(t.x); t.y = tanhf(t.y); t.z = tanhf(t.z); t.w = tanhf(t.w);
            *(float4*)&As[r][c4] = t;
        }
        #pragma unroll
        for (int q = 0; q < 4; ++q) {
            const int fi = tid + 256 * q;
            const int r = fi >> 3, c4 = 4 * (fi & 7);
            *(float4*)&Bs[r][c4] = *(const float4*)&w[(size_t)(col0 + r) * CDIM + k0 + c4];
        }
        __syncthreads();

        #pragma unroll 2
        for (int kk = 0; kk < 32; kk += 4) {
            float4 a4[4];
            #pragma unroll
            for (int i = 0; i < 4; ++i) a4[i] = *(const float4*)&As[ty + 16*i][kk];
            #pragma unroll
            for (int jh = 0; jh < 2; ++jh) {
                float4 b4[4];
                #pragma unroll
                for (int jj = 0; jj < 4; ++jj)
                    b4[jj] = *(const float4*)&Bs[tx + 16*(4*jh + jj)][kk];
                #pragma unroll
                for (int i = 0; i < 4; ++i)
                    #pragma unroll
                    for (int jj = 0; jj < 4; ++jj)
                        acc[i][4*jh + jj] += fabsf(a4[i].x - b4[jj].x) + fabsf(a4[i].y - b4[jj].y)
                                           + fabsf(a4[i].z - b4[jj].z) + fabsf(a4[i].w - b4[jj].w);
            }
        }
    }

    float gcol[8];
    #pragma unroll
    for (int j = 0; j < 8; ++j) gcol[j] = gain[col0 + tx + 16*j];

    #pragma unroll
    for (int i = 0; i < 4; ++i) {
        const int r = row0 + ty + 16*i;
        #pragma unroll
        for (int j = 0; j < 8; ++j) {
            const int c = col0 + tx + 16*j;
            float val = (0.5f - acc[i][j] * (1.0f / 512.0f)) * gcol[j];
            if (z < 2) val = tanhf(val);
            outp[(size_t)r * CDIM + c] = val;
        }
    }
}

// ---------------------------------------------------------------------------
// Kernel 2: causal L1-kernel attention — 512 threads (8 waves).
// R19: Q (only) staged in LDS as bf16 -> 52 KB LDS -> 3 blocks/CU (24 waves,
// 6/SIMD) and the full 640-block grid is co-resident (768 slots, no tail).
// K/V/W stay fp32 — R15 showed inner-loop K unpack costs > occupancy gain;
// Q unpack is on the per-thread (non-broadcast) path and is only +16 cvt per
// score step. `#pragma unroll 2` pragmas are load-bearing (R17: full unroll
// spilled 447 MB). Direct global->LDS staging (R12: named reg arrays crossing
// barriers spill).
// ---------------------------------------------------------------------------
__global__ __launch_bounds__(512, 1) void attn_l1(
    const float* __restrict__ qg, const float* __restrict__ kg, const float* __restrict__ vg,
    const float* __restrict__ gamma, const float* __restrict__ rho,
    float* __restrict__ slabv, float* __restrict__ slabs)
{
    __shared__ unsigned short Qs[128][68];   // bf16, 17408 B
    __shared__ float Vs[64][68];             // 17408 B
    __shared__ float KW[4608];               // union: Ks f32[64][68] / Ws f32[128][36]

    const int bh = blockIdx.x;
    const int b = bh >> 3, h = bh & 7;

    int slot = blockIdx.y;
    int s = 15, c = 0;
    for (;; --s) {
        const int nc = (s >> 2) + 1;
        if (slot < nc) { c = slot; break; }
        slot -= nc;
    }
    const int i0 = s * 128;
    const int ntile = 2 * s + 2;
    const int nch = (s >> 2) + 1;
    const int base = ntile / nch, rem = ntile % nch;
    const int kt0 = c * base + min(c, rem);
    const int kt1 = kt0 + base + (c < rem ? 1 : 0) - 1;

    const int tid = threadIdx.x;
    const int tx = tid & 15, ty = tid >> 4;   // ty 0..31

    const float gp = log1pf(__expf(gamma[h]));
    const float rp = log1pf(__expf(rho[h]));
    const float gp64 = gp * (1.0f / 64.0f);
    const float mrho = -rp;

    const size_t hb = (size_t)b * T_SEQ * CDIM + h * DHEAD;

    // ---- load Q strip (128 x 64) into LDS as bf16 ----
    #pragma unroll
    for (int q = 0; q < 4; ++q) {
        const int fi = tid + 512 * q;             // 0..2047
        const int r = fi >> 4, c4 = 4 * (fi & 15);
        float4 t = *(const float4*)&qg[hb + (size_t)(i0 + r) * CDIM + c4];
        *(ushort4*)&Qs[r][c4] = make_ushort4(f2b(t.x), f2b(t.y), f2b(t.z), f2b(t.w));
    }

    float4 o4[4];
    float accs[4];
    float l1w[4][4];
    #pragma unroll
    for (int i = 0; i < 4; ++i) {
        o4[i] = make_float4(0.f, 0.f, 0.f, 0.f);
        accs[i] = 0.f;
    }

    for (int kt = kt0; kt <= kt1; ++kt) {
        const int j0 = kt * 64;
        __syncthreads();   // prev tile's PV2 done reading KW/Vs; Qs writes done
        #pragma unroll
        for (int q = 0; q < 2; ++q) {
            const int fi = tid + 512 * q;          // 0..1023
            const int r = fi >> 4, c4 = 4 * (fi & 15);
            const size_t off = hb + (size_t)(j0 + r) * CDIM + c4;
            *(float4*)&KW[r * 68 + c4] = *(const float4*)&kg[off];
            *(float4*)&Vs[r][c4]       = *(const float4*)&vg[off];
        }
        __syncthreads();

        #pragma unroll
        for (int i = 0; i < 4; ++i)
            #pragma unroll
            for (int j = 0; j < 4; ++j) l1w[i][j] = 0.f;

        #pragma unroll 2
        for (int d0 = 0; d0 < DHEAD; d0 += 4) {
            float4 a4[4];
            #pragma unroll
            for (int i = 0; i < 4; ++i) {
                const ushort4 u = *(const ushort4*)&Qs[ty + 32*i][d0];
                a4[i] = make_float4(b2f(u.x), b2f(u.y), b2f(u.z), b2f(u.w));
            }
            #pragma unroll
            for (int j = 0; j < 4; ++j) {
                const float4 kx = *(const float4*)&KW[(tx + 16*j) * 68 + d0];
                #pragma unroll
                for (int i = 0; i < 4; ++i)
                    l1w[i][j] += fabsf(a4[i].x - kx.x) + fabsf(a4[i].y - kx.y)
                               + fabsf(a4[i].z - kx.z) + fabsf(a4[i].w - kx.w);
            }
        }

        const bool diag = (kt >= 2 * s);
        #pragma unroll
        for (int i = 0; i < 4; ++i)
            #pragma unroll
            for (int j = 0; j < 4; ++j) {
                const float l1 = l1w[i][j];
                const float den = fmaf(gp64 * l1, l1, 1.000001f);
                float wgt = __builtin_amdgcn_exp2f(mrho * __builtin_amdgcn_logf(den));
                if (diag && (j0 + tx + 16*j) > (i0 + ty + 32*i)) wgt = 0.f;
                l1w[i][j] = wgt;
                accs[i] += wgt;
            }

        #pragma unroll
        for (int hh = 0; hh < 2; ++hh) {
            __syncthreads();
            #pragma unroll
            for (int i = 0; i < 4; ++i) {
                KW[(ty + 32*i) * 36 + tx]      = l1w[i][2*hh];
                KW[(ty + 32*i) * 36 + tx + 16] = l1w[i][2*hh + 1];
            }
            __syncthreads();

            #pragma unroll 2
            for (int jc = 0; jc < 32; jc += 4) {
                float4 w4[4], v4[4];
                #pragma unroll
                for (int i = 0; i < 4; ++i)
                    w4[i] = *(const float4*)&KW[(ty + 32*i) * 36 + jc];
                #pragma unroll
                for (int jj = 0; jj < 4; ++jj)
                    v4[jj] = *(const float4*)&Vs[32*hh + jc + jj][tx*4];
                #pragma unroll
                for (int i = 0; i < 4; ++i) {
                    o4[i].x += w4[i].x*v4[0].x + w4[i].y*v4[1].x + w4[i].z*v4[2].x + w4[i].w*v4[3].x;
                    o4[i].y += w4[i].x*v4[0].y + w4[i].y*v4[1].y + w4[i].z*v4[2].y + w4[i].w*v4[3].y;
                    o4[i].z += w4[i].x*v4[0].z + w4[i].y*v4[1].z + w4[i].z*v4[2].z + w4[i].w*v4[3].z;
                    o4[i].w += w4[i].x*v4[0].w + w4[i].y*v4[1].w + w4[i].z*v4[2].w + w4[i].w*v4[3].w;
                }
            }
        }
    }

    #pragma unroll
    for (int i = 0; i < 4; ++i) {
        accs[i] += __shfl_xor(accs[i], 1, 64);
        accs[i] += __shfl_xor(accs[i], 2, 64);
        accs[i] += __shfl_xor(accs[i], 4, 64);
        accs[i] += __shfl_xor(accs[i], 8, 64);
    }

    float* sv = slabv + (size_t)c * ((size_t)BT * CDIM);
    float* ss = slabs + (size_t)c * ((size_t)BT * HDIM);
    #pragma unroll
    for (int i = 0; i < 4; ++i) {
        const int qr = i0 + ty + 32*i;
        if (tx == 0)
            ss[(size_t)(b * T_SEQ + qr) * HDIM + h] = accs[i];
        *(float4*)&sv[hb + (size_t)qr * CDIM + tx*4] = o4[i];
    }
}

// ---------------------------------------------------------------------------
// Kernel 3: normalize: ab = (sum_c slabv[c]) / (sum_c slabs[c] + 1e-6)
// ---------------------------------------------------------------------------
__global__ __launch_bounds__(256) void normalize_k(
    const float* __restrict__ slabv, const float* __restrict__ slabs,
    float* __restrict__ ab)
{
    int idx = blockIdx.x * 256 + threadIdx.x;   // < 524288 float4
    const int row = idx >> 7;
    const int col = (idx & 127) << 2;
    const int h = col >> 6;
    const int t = row & (T_SEQ - 1);
    const int nch = ((t >> 7) >> 2) + 1;

    const size_t NV = (size_t)BT * CDIM / 4;
    const size_t NS = (size_t)BT * HDIM;
    float4 v = ((const float4*)slabv)[idx];
    float ssum = slabs[(size_t)row * HDIM + h];
    #pragma unroll
    for (int c = 1; c < 4; ++c) {
        if (c < nch) {
            float4 u = ((const float4*)slabv)[c * NV + idx];
            v.x += u.x; v.y += u.y; v.z += u.z; v.w += u.w;
            ssum += slabs[c * NS + (size_t)row * HDIM + h];
        }
    }
    const float inv = 1.0f / (ssum + 1e-6f);
    v.x *= inv; v.y *= inv; v.z *= inv; v.w *= inv;
    ((float4*)ab)[idx] = v;
}

// ---------------------------------------------------------------------------
// Kernel 4: output projection Y = A @ wo^T + bias. 128x64 tile, 8x4 micro.
// ---------------------------------------------------------------------------
__global__ __launch_bounds__(256, 1) void out_gemm(
    const float* __restrict__ A, const float* __restrict__ wo,
    const float* __restrict__ bias, float* __restrict__ Y)
{
    __shared__ float As[128][PSTR];
    __shared__ float Bs[64][PSTR];

    const int row0 = blockIdx.y * 128;
    const int col0 = blockIdx.x * 64;
    const int tid = threadIdx.x;
    const int tx = tid & 15, ty = tid >> 4;
    const int lr = tid >> 3;
    const int lc = (tid & 7) * 4;

    float acc[8][4];
    #pragma unroll
    for (int i = 0; i < 8; ++i)
        #pragma unroll
        for (int j = 0; j < 4; ++j) acc[i][j] = 0.f;

    for (int k0 = 0; k0 < CDIM; k0 += 32) {
        __syncthreads();
        #pragma unroll
        for (int p = 0; p < 4; ++p)
            *(float4*)&As[lr + 32*p][lc] =
                *(const float4*)&A[(size_t)(row0 + lr + 32*p) * CDIM + k0 + lc];
        *(float4*)&Bs[lr][lc] = *(const float4*)&wo[(size_t)(col0 + lr) * CDIM + k0 + lc];
        *(float4*)&Bs[lr + 32][lc] = *(const float4*)&wo[(size_t)(col0 + lr + 32) * CDIM + k0 + lc];
        __syncthreads();

        #pragma unroll
        for (int kk = 0; kk < 32; kk += 4) {
            float4 a4[8], b4[4];
            #pragma unroll
            for (int i = 0; i < 8; ++i) a4[i] = *(const float4*)&As[ty + 16*i][kk];
            #pragma unroll
            for (int j = 0; j < 4; ++j) b4[j] = *(const float4*)&Bs[tx + 16*j][kk];
            #pragma unroll
            for (int i = 0; i < 8; ++i)
                #pragma unroll
                for (int j = 0; j < 4; ++j)
                    acc[i][j] += a4[i].x * b4[j].x + a4[i].y * b4[j].y
                               + a4[i].z * b4[j].z + a4[i].w * b4[j].w;
        }
    }

    float bcol[4];
    #pragma unroll
    for (int j = 0; j < 4; ++j) bcol[j] = bias[col0 + tx + 16*j];

    #pragma unroll
    for (int i = 0; i < 8; ++i) {
        const int r = row0 + ty + 16*i;
        #pragma unroll
        for (int j = 0; j < 4; ++j) {
            const int c = col0 + tx + 16*j;
            Y[(size_t)r * CDIM + c] = acc[i][j] + bcol[j];
        }
    }
}

// ---------------------------------------------------------------------------
extern "C" void kernel_launch(void* const* d_in, const int* in_sizes, int n_in,
                              void* d_out, int out_size, void* d_ws, size_t ws_size,
                              hipStream_t stream)
{
    (void)in_sizes; (void)n_in; (void)out_size; (void)ws_size;
    const float* x     = (const float*)d_in[0];
    // d_in[1] = mask (causal tril; semantics hardcoded)
    const float* wq    = (const float*)d_in[2];
    const float* gq    = (const float*)d_in[3];
    const float* wk    = (const float*)d_in[4];
    const float* gk    = (const float*)d_in[5];
    const float* wv    = (const float*)d_in[6];
    const float* gv    = (const float*)d_in[7];
    const float* wo    = (const float*)d_in[8];
    const float* wob   = (const float*)d_in[9];
    const float* gamma = (const float*)d_in[10];
    const float* rho   = (const float*)d_in[11];
    float* out = (float*)d_out;

    const size_t NV = (size_t)BT * CDIM;   // 2,097,152 floats
    const size_t NW = (size_t)CDIM * CDIM; //   262,144
    const size_t NS = (size_t)BT * HDIM;   //    32,768

    float* ws    = (float*)d_ws;
    float* qb    = ws;                 // NV
    float* kb    = qb + NV;
    float* vb    = kb + NV;
    float* slabv = vb + NV;            // 4*NV
    float* slabs = slabv + 4 * NV;     // 4*NS
    float* wqa   = slabs + 4 * NS;     // NW
    float* wka   = wqa + NW;
    float* wva   = wka + NW;

    wprep<<<768, 256, 0, stream>>>(wq, wk, wv, wqa, wka, wva);
    proj_l1<<<dim3(4, 64, 3), 256, 0, stream>>>(x, wqa, wka, wva,
                                                gq, gk, gv, qb, kb, vb);
    attn_l1<<<dim3(16, 40), 512, 0, stream>>>(qb, kb, vb, gamma, rho, slabv, slabs);
    normalize_k<<<2048, 256, 0, stream>>>(slabv, slabs, qb);  // qb dead -> reuse as ab
    out_gemm<<<dim3(8, 32), 256, 0, stream>>>(qb, wo, wob, out);
}

// Round 20
// 585.431 us; speedup vs baseline: 1.0331x; 1.0331x over previous
//
#include <hip/hip_runtime.h>
#include <hip/hip_bf16.h>

#define T_SEQ 2048
#define CDIM 512
#define HDIM 8
#define DHEAD 64
#define BT 4096   // B*T

// ---------------------------------------------------------------------------
// Kernel 0: tanh of the three weight matrices (once; 3*512*512 values).
// ---------------------------------------------------------------------------
__global__ __launch_bounds__(256) void wprep(
    const float* __restrict__ wq, const float* __restrict__ wk, const float* __restrict__ wv,
    float* __restrict__ wqa, float* __restrict__ wka, float* __restrict__ wva)
{
    const int NW = CDIM * CDIM / 4;   // 65536 float4 per matrix
    int idx = blockIdx.x * 256 + threadIdx.x;
    const float4* src; float4* dst; int off;
    if (idx < NW)            { src = (const float4*)wq; dst = (float4*)wqa; off = idx; }
    else if (idx < 2 * NW)   { src = (const float4*)wk; dst = (float4*)wka; off = idx - NW; }
    else                     { src = (const float4*)wv; dst = (float4*)wva; off = idx - 2 * NW; }
    float4 t = src[off];
    t.x = tanhf(t.x); t.y = tanhf(t.y); t.z = tanhf(t.z); t.w = tanhf(t.w);
    dst[off] = t;
}

// ---------------------------------------------------------------------------
// Kernel 1: L1-cdist projection. x-tanh fused into A-staging; weights
// pre-tanh'd by wprep. 64x128 tile, 256 threads, 4x8 micro-tile. (256,1).
// ---------------------------------------------------------------------------
#define PSTR 36
__global__ __launch_bounds__(256, 1) void proj_l1(
    const float* __restrict__ x,
    const float* __restrict__ wqa, const float* __restrict__ wka, const float* __restrict__ wva,
    const float* __restrict__ gq,  const float* __restrict__ gk,  const float* __restrict__ gv,
    float* __restrict__ oq, float* __restrict__ okk, float* __restrict__ ov)
{
    __shared__ float As[64][PSTR];
    __shared__ float Bs[128][PSTR];

    const int z = blockIdx.z;
    const float* w    = (z == 0) ? wqa : (z == 1) ? wka : wva;
    const float* gain = (z == 0) ? gq  : (z == 1) ? gk  : gv;
    float* outp       = (z == 0) ? oq  : (z == 1) ? okk : ov;

    const int row0 = blockIdx.y * 64;
    const int col0 = blockIdx.x * 128;
    const int tid = threadIdx.x;
    const int tx = tid & 15, ty = tid >> 4;

    float acc[4][8];
    #pragma unroll
    for (int i = 0; i < 4; ++i)
        #pragma unroll
        for (int j = 0; j < 8; ++j) acc[i][j] = 0.f;

    for (int k0 = 0; k0 < CDIM; k0 += 32) {
        __syncthreads();
        #pragma unroll
        for (int q = 0; q < 2; ++q) {
            const int fi = tid + 256 * q;
            const int r = fi >> 3, c4 = 4 * (fi & 7);
            float4 t = *(const float4*)&x[(size_t)(row0 + r) * CDIM + k0 + c4];
            t.x = tanhf(t.x); t.y = tanhf(t.y); t.z = tanhf(t.z); t.w = tanhf(t.w);
            *(float4*)&As[r][c4] = t;
        }
        #pragma unroll
        for (int q = 0; q < 4; ++q) {
            const int fi = tid + 256 * q;
            const int r = fi >> 3, c4 = 4 * (fi & 7);
            *(float4*)&Bs[r][c4] = *(const float4*)&w[(size_t)(col0 + r) * CDIM + k0 + c4];
        }
        __syncthreads();

        #pragma unroll 2
        for (int kk = 0; kk < 32; kk += 4) {
            float4 a4[4];
            #pragma unroll
            for (int i = 0; i < 4; ++i) a4[i] = *(const float4*)&As[ty + 16*i][kk];
            #pragma unroll
            for (int jh = 0; jh < 2; ++jh) {
                float4 b4[4];
                #pragma unroll
                for (int jj = 0; jj < 4; ++jj)
                    b4[jj] = *(const float4*)&Bs[tx + 16*(4*jh + jj)][kk];
                #pragma unroll
                for (int i = 0; i < 4; ++i)
                    #pragma unroll
                    for (int jj = 0; jj < 4; ++jj)
                        acc[i][4*jh + jj] += fabsf(a4[i].x - b4[jj].x) + fabsf(a4[i].y - b4[jj].y)
                                           + fabsf(a4[i].z - b4[jj].z) + fabsf(a4[i].w - b4[jj].w);
            }
        }
    }

    float gcol[8];
    #pragma unroll
    for (int j = 0; j < 8; ++j) gcol[j] = gain[col0 + tx + 16*j];

    #pragma unroll
    for (int i = 0; i < 4; ++i) {
        const int r = row0 + ty + 16*i;
        #pragma unroll
        for (int j = 0; j < 8; ++j) {
            const int c = col0 + tx + 16*j;
            float val = (0.5f - acc[i][j] * (1.0f / 512.0f)) * gcol[j];
            if (z < 2) val = tanhf(val);
            outp[(size_t)r * CDIM + c] = val;
        }
    }
}

// ---------------------------------------------------------------------------
// Kernel 2: causal L1-kernel attention — 512 threads (8 waves), fp32.
// EXACT R16/R18 body (measured 307 us, VALUBusy 66.8%, VGPR 56, WRITE 23 MB).
// Known-dead directions (measured): full unroll spills 447 MB (R17); bf16
// K/V (R15) or Q-only (R19) operands add inner-loop cvt that outweighs LDS
// savings (grid 640 < 3-block capacity 768, so occupancy cannot rise);
// named reg arrays crossing barriers spill (R7-R11).
// ---------------------------------------------------------------------------
__global__ __launch_bounds__(512, 1) void attn_l1(
    const float* __restrict__ qg, const float* __restrict__ kg, const float* __restrict__ vg,
    const float* __restrict__ gamma, const float* __restrict__ rho,
    float* __restrict__ slabv, float* __restrict__ slabs)
{
    __shared__ float Qs[128][68];
    __shared__ float Vs[64][68];
    __shared__ float KW[4608];   // union: Ks f32[64][68] (4352) / Ws f32[128][36] (4608)

    const int bh = blockIdx.x;
    const int b = bh >> 3, h = bh & 7;

    int slot = blockIdx.y;
    int s = 15, c = 0;
    for (;; --s) {
        const int nc = (s >> 2) + 1;
        if (slot < nc) { c = slot; break; }
        slot -= nc;
    }
    const int i0 = s * 128;
    const int ntile = 2 * s + 2;
    const int nch = (s >> 2) + 1;
    const int base = ntile / nch, rem = ntile % nch;
    const int kt0 = c * base + min(c, rem);
    const int kt1 = kt0 + base + (c < rem ? 1 : 0) - 1;

    const int tid = threadIdx.x;
    const int tx = tid & 15, ty = tid >> 4;   // ty 0..31

    const float gp = log1pf(__expf(gamma[h]));
    const float rp = log1pf(__expf(rho[h]));
    const float gp64 = gp * (1.0f / 64.0f);
    const float mrho = -rp;

    const size_t hb = (size_t)b * T_SEQ * CDIM + h * DHEAD;

    #pragma unroll
    for (int q = 0; q < 4; ++q) {
        const int fi = tid + 512 * q;             // 0..2047
        const int r = fi >> 4, c4 = 4 * (fi & 15);
        *(float4*)&Qs[r][c4] = *(const float4*)&qg[hb + (size_t)(i0 + r) * CDIM + c4];
    }

    float4 o4[4];
    float accs[4];
    float l1w[4][4];
    #pragma unroll
    for (int i = 0; i < 4; ++i) {
        o4[i] = make_float4(0.f, 0.f, 0.f, 0.f);
        accs[i] = 0.f;
    }

    for (int kt = kt0; kt <= kt1; ++kt) {
        const int j0 = kt * 64;
        __syncthreads();   // prev tile's PV2 done reading KW/Vs; Qs writes done
        #pragma unroll
        for (int q = 0; q < 2; ++q) {
            const int fi = tid + 512 * q;          // 0..1023
            const int r = fi >> 4, c4 = 4 * (fi & 15);
            const size_t off = hb + (size_t)(j0 + r) * CDIM + c4;
            *(float4*)&KW[r * 68 + c4] = *(const float4*)&kg[off];
            *(float4*)&Vs[r][c4]       = *(const float4*)&vg[off];
        }
        __syncthreads();

        #pragma unroll
        for (int i = 0; i < 4; ++i)
            #pragma unroll
            for (int j = 0; j < 4; ++j) l1w[i][j] = 0.f;

        #pragma unroll 2
        for (int d0 = 0; d0 < DHEAD; d0 += 4) {
            float4 a4[4];
            #pragma unroll
            for (int i = 0; i < 4; ++i) a4[i] = *(const float4*)&Qs[ty + 32*i][d0];
            #pragma unroll
            for (int j = 0; j < 4; ++j) {
                const float4 kx = *(const float4*)&KW[(tx + 16*j) * 68 + d0];
                #pragma unroll
                for (int i = 0; i < 4; ++i)
                    l1w[i][j] += fabsf(a4[i].x - kx.x) + fabsf(a4[i].y - kx.y)
                               + fabsf(a4[i].z - kx.z) + fabsf(a4[i].w - kx.w);
            }
        }

        const bool diag = (kt >= 2 * s);
        #pragma unroll
        for (int i = 0; i < 4; ++i)
            #pragma unroll
            for (int j = 0; j < 4; ++j) {
                const float l1 = l1w[i][j];
                const float den = fmaf(gp64 * l1, l1, 1.000001f);
                float wgt = __builtin_amdgcn_exp2f(mrho * __builtin_amdgcn_logf(den));
                if (diag && (j0 + tx + 16*j) > (i0 + ty + 32*i)) wgt = 0.f;
                l1w[i][j] = wgt;
                accs[i] += wgt;
            }

        #pragma unroll
        for (int hh = 0; hh < 2; ++hh) {
            __syncthreads();
            #pragma unroll
            for (int i = 0; i < 4; ++i) {
                KW[(ty + 32*i) * 36 + tx]      = l1w[i][2*hh];
                KW[(ty + 32*i) * 36 + tx + 16] = l1w[i][2*hh + 1];
            }
            __syncthreads();

            #pragma unroll 2
            for (int jc = 0; jc < 32; jc += 4) {
                float4 w4[4], v4[4];
                #pragma unroll
                for (int i = 0; i < 4; ++i)
                    w4[i] = *(const float4*)&KW[(ty + 32*i) * 36 + jc];
                #pragma unroll
                for (int jj = 0; jj < 4; ++jj)
                    v4[jj] = *(const float4*)&Vs[32*hh + jc + jj][tx*4];
                #pragma unroll
                for (int i = 0; i < 4; ++i) {
                    o4[i].x += w4[i].x*v4[0].x + w4[i].y*v4[1].x + w4[i].z*v4[2].x + w4[i].w*v4[3].x;
                    o4[i].y += w4[i].x*v4[0].y + w4[i].y*v4[1].y + w4[i].z*v4[2].y + w4[i].w*v4[3].y;
                    o4[i].z += w4[i].x*v4[0].z + w4[i].y*v4[1].z + w4[i].z*v4[2].z + w4[i].w*v4[3].z;
                    o4[i].w += w4[i].x*v4[0].w + w4[i].y*v4[1].w + w4[i].z*v4[2].w + w4[i].w*v4[3].w;
                }
            }
        }
    }

    #pragma unroll
    for (int i = 0; i < 4; ++i) {
        accs[i] += __shfl_xor(accs[i], 1, 64);
        accs[i] += __shfl_xor(accs[i], 2, 64);
        accs[i] += __shfl_xor(accs[i], 4, 64);
        accs[i] += __shfl_xor(accs[i], 8, 64);
    }

    float* sv = slabv + (size_t)c * ((size_t)BT * CDIM);
    float* ss = slabs + (size_t)c * ((size_t)BT * HDIM);
    #pragma unroll
    for (int i = 0; i < 4; ++i) {
        const int qr = i0 + ty + 32*i;
        if (tx == 0)
            ss[(size_t)(b * T_SEQ + qr) * HDIM + h] = accs[i];
        *(float4*)&sv[hb + (size_t)qr * CDIM + tx*4] = o4[i];
    }
}

// ---------------------------------------------------------------------------
// Kernel 3: normalize: ab = (sum_c slabv[c]) / (sum_c slabs[c] + 1e-6)
// ---------------------------------------------------------------------------
__global__ __launch_bounds__(256) void normalize_k(
    const float* __restrict__ slabv, const float* __restrict__ slabs,
    float* __restrict__ ab)
{
    int idx = blockIdx.x * 256 + threadIdx.x;   // < 524288 float4
    const int row = idx >> 7;
    const int col = (idx & 127) << 2;
    const int h = col >> 6;
    const int t = row & (T_SEQ - 1);
    const int nch = ((t >> 7) >> 2) + 1;

    const size_t NV = (size_t)BT * CDIM / 4;
    const size_t NS = (size_t)BT * HDIM;
    float4 v = ((const float4*)slabv)[idx];
    float ssum = slabs[(size_t)row * HDIM + h];
    #pragma unroll
    for (int c = 1; c < 4; ++c) {
        if (c < nch) {
            float4 u = ((const float4*)slabv)[c * NV + idx];
            v.x += u.x; v.y += u.y; v.z += u.z; v.w += u.w;
            ssum += slabs[c * NS + (size_t)row * HDIM + h];
        }
    }
    const float inv = 1.0f / (ssum + 1e-6f);
    v.x *= inv; v.y *= inv; v.z *= inv; v.w *= inv;
    ((float4*)ab)[idx] = v;
}

// ---------------------------------------------------------------------------
// Kernel 4: output projection Y = A @ wo^T + bias. 128x64 tile, 8x4 micro.
// ---------------------------------------------------------------------------
__global__ __launch_bounds__(256, 1) void out_gemm(
    const float* __restrict__ A, const float* __restrict__ wo,
    const float* __restrict__ bias, float* __restrict__ Y)
{
    __shared__ float As[128][PSTR];
    __shared__ float Bs[64][PSTR];

    const int row0 = blockIdx.y * 128;
    const int col0 = blockIdx.x * 64;
    const int tid = threadIdx.x;
    const int tx = tid & 15, ty = tid >> 4;
    const int lr = tid >> 3;
    const int lc = (tid & 7) * 4;

    float acc[8][4];
    #pragma unroll
    for (int i = 0; i < 8; ++i)
        #pragma unroll
        for (int j = 0; j < 4; ++j) acc[i][j] = 0.f;

    for (int k0 = 0; k0 < CDIM; k0 += 32) {
        __syncthreads();
        #pragma unroll
        for (int p = 0; p < 4; ++p)
            *(float4*)&As[lr + 32*p][lc] =
                *(const float4*)&A[(size_t)(row0 + lr + 32*p) * CDIM + k0 + lc];
        *(float4*)&Bs[lr][lc] = *(const float4*)&wo[(size_t)(col0 + lr) * CDIM + k0 + lc];
        *(float4*)&Bs[lr + 32][lc] = *(const float4*)&wo[(size_t)(col0 + lr + 32) * CDIM + k0 + lc];
        __syncthreads();

        #pragma unroll
        for (int kk = 0; kk < 32; kk += 4) {
            float4 a4[8], b4[4];
            #pragma unroll
            for (int i = 0; i < 8; ++i) a4[i] = *(const float4*)&As[ty + 16*i][kk];
            #pragma unroll
            for (int j = 0; j < 4; ++j) b4[j] = *(const float4*)&Bs[tx + 16*j][kk];
            #pragma unroll
            for (int i = 0; i < 8; ++i)
                #pragma unroll
                for (int j = 0; j < 4; ++j)
                    acc[i][j] += a4[i].x * b4[j].x + a4[i].y * b4[j].y
                               + a4[i].z * b4[j].z + a4[i].w * b4[j].w;
        }
    }

    float bcol[4];
    #pragma unroll
    for (int j = 0; j < 4; ++j) bcol[j] = bias[col0 + tx + 16*j];

    #pragma unroll
    for (int i = 0; i < 8; ++i) {
        const int r = row0 + ty + 16*i;
        #pragma unroll
        for (int j = 0; j < 4; ++j) {
            const int c = col0 + tx + 16*j;
            Y[(size_t)r * CDIM + c] = acc[i][j] + bcol[j];
        }
    }
}

// ---------------------------------------------------------------------------
extern "C" void kernel_launch(void* const* d_in, const int* in_sizes, int n_in,
                              void* d_out, int out_size, void* d_ws, size_t ws_size,
                              hipStream_t stream)
{
    (void)in_sizes; (void)n_in; (void)out_size; (void)ws_size;
    const float* x     = (const float*)d_in[0];
    // d_in[1] = mask (causal tril; semantics hardcoded)
    const float* wq    = (const float*)d_in[2];
    const float* gq    = (const float*)d_in[3];
    const float* wk    = (const float*)d_in[4];
    const float* gk    = (const float*)d_in[5];
    const float* wv    = (const float*)d_in[6];
    const float* gv    = (const float*)d_in[7];
    const float* wo    = (const float*)d_in[8];
    const float* wob   = (const float*)d_in[9];
    const float* gamma = (const float*)d_in[10];
    const float* rho   = (const float*)d_in[11];
    float* out = (float*)d_out;

    const size_t NV = (size_t)BT * CDIM;   // 2,097,152 floats
    const size_t NW = (size_t)CDIM * CDIM; //   262,144
    const size_t NS = (size_t)BT * HDIM;   //    32,768

    float* ws    = (float*)d_ws;
    float* qb    = ws;                 // NV
    float* kb    = qb + NV;
    float* vb    = kb + NV;
    float* slabv = vb + NV;            // 4*NV
    float* slabs = slabv + 4 * NV;     // 4*NS
    float* wqa   = slabs + 4 * NS;     // NW
    float* wka   = wqa + NW;
    float* wva   = wka + NW;

    wprep<<<768, 256, 0, stream>>>(wq, wk, wv, wqa, wka, wva);
    proj_l1<<<dim3(4, 64, 3), 256, 0, stream>>>(x, wqa, wka, wva,
                                                gq, gk, gv, qb, kb, vb);
    attn_l1<<<dim3(16, 40), 512, 0, stream>>>(qb, kb, vb, gamma, rho, slabv, slabs);
    normalize_k<<<2048, 256, 0, stream>>>(slabv, slabs, qb);  // qb dead -> reuse as ab
    out_gemm<<<dim3(8, 32), 256, 0, stream>>>(qb, wo, wob, out);
}

// Round 21
// 571.480 us; speedup vs baseline: 1.0584x; 1.0244x over previous
//
#include <hip/hip_runtime.h>
#include <hip/hip_bf16.h>

#define T_SEQ 2048
#define CDIM 512
#define HDIM 8
#define DHEAD 64
#define BT 4096   // B*T

// ---------------------------------------------------------------------------
// Kernel 0: tanh of the three weight matrices (once; 3*512*512 values).
// ---------------------------------------------------------------------------
__global__ __launch_bounds__(256) void wprep(
    const float* __restrict__ wq, const float* __restrict__ wk, const float* __restrict__ wv,
    float* __restrict__ wqa, float* __restrict__ wka, float* __restrict__ wva)
{
    const int NW = CDIM * CDIM / 4;   // 65536 float4 per matrix
    int idx = blockIdx.x * 256 + threadIdx.x;
    const float4* src; float4* dst; int off;
    if (idx < NW)            { src = (const float4*)wq; dst = (float4*)wqa; off = idx; }
    else if (idx < 2 * NW)   { src = (const float4*)wk; dst = (float4*)wka; off = idx - NW; }
    else                     { src = (const float4*)wv; dst = (float4*)wva; off = idx - 2 * NW; }
    float4 t = src[off];
    t.x = tanhf(t.x); t.y = tanhf(t.y); t.z = tanhf(t.z); t.w = tanhf(t.w);
    dst[off] = t;
}

// ---------------------------------------------------------------------------
// Kernel 1: L1-cdist projection. x-tanh fused into A-staging; weights
// pre-tanh'd by wprep. 64x128 tile, 256 threads, 4x8 micro-tile. (256,1).
// ---------------------------------------------------------------------------
#define PSTR 36
__global__ __launch_bounds__(256, 1) void proj_l1(
    const float* __restrict__ x,
    const float* __restrict__ wqa, const float* __restrict__ wka, const float* __restrict__ wva,
    const float* __restrict__ gq,  const float* __restrict__ gk,  const float* __restrict__ gv,
    float* __restrict__ oq, float* __restrict__ okk, float* __restrict__ ov)
{
    __shared__ float As[64][PSTR];
    __shared__ float Bs[128][PSTR];

    const int z = blockIdx.z;
    const float* w    = (z == 0) ? wqa : (z == 1) ? wka : wva;
    const float* gain = (z == 0) ? gq  : (z == 1) ? gk  : gv;
    float* outp       = (z == 0) ? oq  : (z == 1) ? okk : ov;

    const int row0 = blockIdx.y * 64;
    const int col0 = blockIdx.x * 128;
    const int tid = threadIdx.x;
    const int tx = tid & 15, ty = tid >> 4;

    float acc[4][8];
    #pragma unroll
    for (int i = 0; i < 4; ++i)
        #pragma unroll
        for (int j = 0; j < 8; ++j) acc[i][j] = 0.f;

    for (int k0 = 0; k0 < CDIM; k0 += 32) {
        __syncthreads();
        #pragma unroll
        for (int q = 0; q < 2; ++q) {
            const int fi = tid + 256 * q;
            const int r = fi >> 3, c4 = 4 * (fi & 7);
            float4 t = *(const float4*)&x[(size_t)(row0 + r) * CDIM + k0 + c4];
            t.x = tanhf(t.x); t.y = tanhf(t.y); t.z = tanhf(t.z); t.w = tanhf(t.w);
            *(float4*)&As[r][c4] = t;
        }
        #pragma unroll
        for (int q = 0; q < 4; ++q) {
            const int fi = tid + 256 * q;
            const int r = fi >> 3, c4 = 4 * (fi & 7);
            *(float4*)&Bs[r][c4] = *(const float4*)&w[(size_t)(col0 + r) * CDIM + k0 + c4];
        }
        __syncthreads();

        #pragma unroll 2
        for (int kk = 0; kk < 32; kk += 4) {
            float4 a4[4];
            #pragma unroll
            for (int i = 0; i < 4; ++i) a4[i] = *(const float4*)&As[ty + 16*i][kk];
            #pragma unroll
            for (int jh = 0; jh < 2; ++jh) {
                float4 b4[4];
                #pragma unroll
                for (int jj = 0; jj < 4; ++jj)
                    b4[jj] = *(const float4*)&Bs[tx + 16*(4*jh + jj)][kk];
                #pragma unroll
                for (int i = 0; i < 4; ++i)
                    #pragma unroll
                    for (int jj = 0; jj < 4; ++jj)
                        acc[i][4*jh + jj] += fabsf(a4[i].x - b4[jj].x) + fabsf(a4[i].y - b4[jj].y)
                                           + fabsf(a4[i].z - b4[jj].z) + fabsf(a4[i].w - b4[jj].w);
            }
        }
    }

    float gcol[8];
    #pragma unroll
    for (int j = 0; j < 8; ++j) gcol[j] = gain[col0 + tx + 16*j];

    #pragma unroll
    for (int i = 0; i < 4; ++i) {
        const int r = row0 + ty + 16*i;
        #pragma unroll
        for (int j = 0; j < 8; ++j) {
            const int c = col0 + tx + 16*j;
            float val = (0.5f - acc[i][j] * (1.0f / 512.0f)) * gcol[j];
            if (z < 2) val = tanhf(val);
            outp[(size_t)r * CDIM + c] = val;
        }
    }
}

// ---------------------------------------------------------------------------
// Kernel 2: causal L1-kernel attention — 512 threads (8 waves), fp32.
// EXACT R16/R18/R20 body (measured 307 us, VALUBusy 66.8%, VGPR 56).
// Known-dead directions (measured): full unroll spills 447 MB (R17); bf16
// operands add inner-loop cvt that outweighs LDS savings (R15/R19); named
// reg arrays crossing barriers spill (R7-R11). Do not modify.
// ---------------------------------------------------------------------------
__global__ __launch_bounds__(512, 1) void attn_l1(
    const float* __restrict__ qg, const float* __restrict__ kg, const float* __restrict__ vg,
    const float* __restrict__ gamma, const float* __restrict__ rho,
    float* __restrict__ slabv, float* __restrict__ slabs)
{
    __shared__ float Qs[128][68];
    __shared__ float Vs[64][68];
    __shared__ float KW[4608];   // union: Ks f32[64][68] (4352) / Ws f32[128][36] (4608)

    const int bh = blockIdx.x;
    const int b = bh >> 3, h = bh & 7;

    int slot = blockIdx.y;
    int s = 15, c = 0;
    for (;; --s) {
        const int nc = (s >> 2) + 1;
        if (slot < nc) { c = slot; break; }
        slot -= nc;
    }
    const int i0 = s * 128;
    const int ntile = 2 * s + 2;
    const int nch = (s >> 2) + 1;
    const int base = ntile / nch, rem = ntile % nch;
    const int kt0 = c * base + min(c, rem);
    const int kt1 = kt0 + base + (c < rem ? 1 : 0) - 1;

    const int tid = threadIdx.x;
    const int tx = tid & 15, ty = tid >> 4;   // ty 0..31

    const float gp = log1pf(__expf(gamma[h]));
    const float rp = log1pf(__expf(rho[h]));
    const float gp64 = gp * (1.0f / 64.0f);
    const float mrho = -rp;

    const size_t hb = (size_t)b * T_SEQ * CDIM + h * DHEAD;

    #pragma unroll
    for (int q = 0; q < 4; ++q) {
        const int fi = tid + 512 * q;             // 0..2047
        const int r = fi >> 4, c4 = 4 * (fi & 15);
        *(float4*)&Qs[r][c4] = *(const float4*)&qg[hb + (size_t)(i0 + r) * CDIM + c4];
    }

    float4 o4[4];
    float accs[4];
    float l1w[4][4];
    #pragma unroll
    for (int i = 0; i < 4; ++i) {
        o4[i] = make_float4(0.f, 0.f, 0.f, 0.f);
        accs[i] = 0.f;
    }

    for (int kt = kt0; kt <= kt1; ++kt) {
        const int j0 = kt * 64;
        __syncthreads();   // prev tile's PV2 done reading KW/Vs; Qs writes done
        #pragma unroll
        for (int q = 0; q < 2; ++q) {
            const int fi = tid + 512 * q;          // 0..1023
            const int r = fi >> 4, c4 = 4 * (fi & 15);
            const size_t off = hb + (size_t)(j0 + r) * CDIM + c4;
            *(float4*)&KW[r * 68 + c4] = *(const float4*)&kg[off];
            *(float4*)&Vs[r][c4]       = *(const float4*)&vg[off];
        }
        __syncthreads();

        #pragma unroll
        for (int i = 0; i < 4; ++i)
            #pragma unroll
            for (int j = 0; j < 4; ++j) l1w[i][j] = 0.f;

        #pragma unroll 2
        for (int d0 = 0; d0 < DHEAD; d0 += 4) {
            float4 a4[4];
            #pragma unroll
            for (int i = 0; i < 4; ++i) a4[i] = *(const float4*)&Qs[ty + 32*i][d0];
            #pragma unroll
            for (int j = 0; j < 4; ++j) {
                const float4 kx = *(const float4*)&KW[(tx + 16*j) * 68 + d0];
                #pragma unroll
                for (int i = 0; i < 4; ++i)
                    l1w[i][j] += fabsf(a4[i].x - kx.x) + fabsf(a4[i].y - kx.y)
                               + fabsf(a4[i].z - kx.z) + fabsf(a4[i].w - kx.w);
            }
        }

        const bool diag = (kt >= 2 * s);
        #pragma unroll
        for (int i = 0; i < 4; ++i)
            #pragma unroll
            for (int j = 0; j < 4; ++j) {
                const float l1 = l1w[i][j];
                const float den = fmaf(gp64 * l1, l1, 1.000001f);
                float wgt = __builtin_amdgcn_exp2f(mrho * __builtin_amdgcn_logf(den));
                if (diag && (j0 + tx + 16*j) > (i0 + ty + 32*i)) wgt = 0.f;
                l1w[i][j] = wgt;
                accs[i] += wgt;
            }

        #pragma unroll
        for (int hh = 0; hh < 2; ++hh) {
            __syncthreads();
            #pragma unroll
            for (int i = 0; i < 4; ++i) {
                KW[(ty + 32*i) * 36 + tx]      = l1w[i][2*hh];
                KW[(ty + 32*i) * 36 + tx + 16] = l1w[i][2*hh + 1];
            }
            __syncthreads();

            #pragma unroll 2
            for (int jc = 0; jc < 32; jc += 4) {
                float4 w4[4], v4[4];
                #pragma unroll
                for (int i = 0; i < 4; ++i)
                    w4[i] = *(const float4*)&KW[(ty + 32*i) * 36 + jc];
                #pragma unroll
                for (int jj = 0; jj < 4; ++jj)
                    v4[jj] = *(const float4*)&Vs[32*hh + jc + jj][tx*4];
                #pragma unroll
                for (int i = 0; i < 4; ++i) {
                    o4[i].x += w4[i].x*v4[0].x + w4[i].y*v4[1].x + w4[i].z*v4[2].x + w4[i].w*v4[3].x;
                    o4[i].y += w4[i].x*v4[0].y + w4[i].y*v4[1].y + w4[i].z*v4[2].y + w4[i].w*v4[3].y;
                    o4[i].z += w4[i].x*v4[0].z + w4[i].y*v4[1].z + w4[i].z*v4[2].z + w4[i].w*v4[3].z;
                    o4[i].w += w4[i].x*v4[0].w + w4[i].y*v4[1].w + w4[i].z*v4[2].w + w4[i].w*v4[3].w;
                }
            }
        }
    }

    #pragma unroll
    for (int i = 0; i < 4; ++i) {
        accs[i] += __shfl_xor(accs[i], 1, 64);
        accs[i] += __shfl_xor(accs[i], 2, 64);
        accs[i] += __shfl_xor(accs[i], 4, 64);
        accs[i] += __shfl_xor(accs[i], 8, 64);
    }

    float* sv = slabv + (size_t)c * ((size_t)BT * CDIM);
    float* ss = slabs + (size_t)c * ((size_t)BT * HDIM);
    #pragma unroll
    for (int i = 0; i < 4; ++i) {
        const int qr = i0 + ty + 32*i;
        if (tx == 0)
            ss[(size_t)(b * T_SEQ + qr) * HDIM + h] = accs[i];
        *(float4*)&sv[hb + (size_t)qr * CDIM + tx*4] = o4[i];
    }
}

// ---------------------------------------------------------------------------
// Kernel 3: normalize: ab = (sum_c slabv[c]) / (sum_c slabs[c] + 1e-6)
// ---------------------------------------------------------------------------
__global__ __launch_bounds__(256) void normalize_k(
    const float* __restrict__ slabv, const float* __restrict__ slabs,
    float* __restrict__ ab)
{
    int idx = blockIdx.x * 256 + threadIdx.x;   // < 524288 float4
    const int row = idx >> 7;
    const int col = (idx & 127) << 2;
    const int h = col >> 6;
    const int t = row & (T_SEQ - 1);
    const int nch = ((t >> 7) >> 2) + 1;

    const size_t NV = (size_t)BT * CDIM / 4;
    const size_t NS = (size_t)BT * HDIM;
    float4 v = ((const float4*)slabv)[idx];
    float ssum = slabs[(size_t)row * HDIM + h];
    #pragma unroll
    for (int c = 1; c < 4; ++c) {
        if (c < nch) {
            float4 u = ((const float4*)slabv)[c * NV + idx];
            v.x += u.x; v.y += u.y; v.z += u.z; v.w += u.w;
            ssum += slabs[c * NS + (size_t)row * HDIM + h];
        }
    }
    const float inv = 1.0f / (ssum + 1e-6f);
    v.x *= inv; v.y *= inv; v.z *= inv; v.w *= inv;
    ((float4*)ab)[idx] = v;
}

// ---------------------------------------------------------------------------
// Kernel 4: output projection Y = A @ wo^T + bias.
// R21: 64x64 tile, 4x4 stride-16 micro, grid (8,64)=512 blocks = 2/CU
// (vs 1/CU at 128x64) — second resident block fills k0-loop barrier gaps.
// Direct global->LDS staging (R12 pattern, no cross-barrier reg state).
// ---------------------------------------------------------------------------
__global__ __launch_bounds__(256, 1) void out_gemm(
    const float* __restrict__ A, const float* __restrict__ wo,
    const float* __restrict__ bias, float* __restrict__ Y)
{
    __shared__ float As[64][PSTR];
    __shared__ float Bs[64][PSTR];

    const int row0 = blockIdx.y * 64;
    const int col0 = blockIdx.x * 64;
    const int tid = threadIdx.x;
    const int tx = tid & 15, ty = tid >> 4;

    float acc[4][4];
    #pragma unroll
    for (int i = 0; i < 4; ++i)
        #pragma unroll
        for (int j = 0; j < 4; ++j) acc[i][j] = 0.f;

    for (int k0 = 0; k0 < CDIM; k0 += 32) {
        __syncthreads();
        #pragma unroll
        for (int q = 0; q < 2; ++q) {
            const int fi = tid + 256 * q;
            const int r = fi >> 3, c4 = 4 * (fi & 7);
            *(float4*)&As[r][c4] = *(const float4*)&A[(size_t)(row0 + r) * CDIM + k0 + c4];
            *(float4*)&Bs[r][c4] = *(const float4*)&wo[(size_t)(col0 + r) * CDIM + k0 + c4];
        }
        __syncthreads();

        #pragma unroll 2
        for (int kk = 0; kk < 32; kk += 4) {
            float4 a4[4], b4[4];
            #pragma unroll
            for (int i = 0; i < 4; ++i) a4[i] = *(const float4*)&As[ty + 16*i][kk];
            #pragma unroll
            for (int j = 0; j < 4; ++j) b4[j] = *(const float4*)&Bs[tx + 16*j][kk];
            #pragma unroll
            for (int i = 0; i < 4; ++i)
                #pragma unroll
                for (int j = 0; j < 4; ++j)
                    acc[i][j] += a4[i].x * b4[j].x + a4[i].y * b4[j].y
                               + a4[i].z * b4[j].z + a4[i].w * b4[j].w;
        }
    }

    float bcol[4];
    #pragma unroll
    for (int j = 0; j < 4; ++j) bcol[j] = bias[col0 + tx + 16*j];

    #pragma unroll
    for (int i = 0; i < 4; ++i) {
        const int r = row0 + ty + 16*i;
        #pragma unroll
        for (int j = 0; j < 4; ++j) {
            const int c = col0 + tx + 16*j;
            Y[(size_t)r * CDIM + c] = acc[i][j] + bcol[j];
        }
    }
}

// ---------------------------------------------------------------------------
extern "C" void kernel_launch(void* const* d_in, const int* in_sizes, int n_in,
                              void* d_out, int out_size, void* d_ws, size_t ws_size,
                              hipStream_t stream)
{
    (void)in_sizes; (void)n_in; (void)out_size; (void)ws_size;
    const float* x     = (const float*)d_in[0];
    // d_in[1] = mask (causal tril; semantics hardcoded)
    const float* wq    = (const float*)d_in[2];
    const float* gq    = (const float*)d_in[3];
    const float* wk    = (const float*)d_in[4];
    const float* gk    = (const float*)d_in[5];
    const float* wv    = (const float*)d_in[6];
    const float* gv    = (const float*)d_in[7];
    const float* wo    = (const float*)d_in[8];
    const float* wob   = (const float*)d_in[9];
    const float* gamma = (const float*)d_in[10];
    const float* rho   = (const float*)d_in[11];
    float* out = (float*)d_out;

    const size_t NV = (size_t)BT * CDIM;   // 2,097,152 floats
    const size_t NW = (size_t)CDIM * CDIM; //   262,144
    const size_t NS = (size_t)BT * HDIM;   //    32,768

    float* ws    = (float*)d_ws;
    float* qb    = ws;                 // NV
    float* kb    = qb + NV;
    float* vb    = kb + NV;
    float* slabv = vb + NV;            // 4*NV
    float* slabs = slabv + 4 * NV;     // 4*NS
    float* wqa   = slabs + 4 * NS;     // NW
    float* wka   = wqa + NW;
    float* wva   = wka + NW;

    wprep<<<768, 256, 0, stream>>>(wq, wk, wv, wqa, wka, wva);
    proj_l1<<<dim3(4, 64, 3), 256, 0, stream>>>(x, wqa, wka, wva,
                                                gq, gk, gv, qb, kb, vb);
    attn_l1<<<dim3(16, 40), 512, 0, stream>>>(qb, kb, vb, gamma, rho, slabv, slabs);
    normalize_k<<<2048, 256, 0, stream>>>(slabv, slabs, qb);  // qb dead -> reuse as ab
    out_gemm<<<dim3(8, 64), 256, 0, stream>>>(qb, wo, wob, out);
}